// Round 1
// baseline (339.320 us; speedup 1.0000x reference)
//
#include <hip/hip_runtime.h>
#include <stdint.h>

// Tree-LSTM scan: B=256, L=128, STATE=128, INIT=256, Z=5*128=640. fp32 I/O.
// Pipeline:
//  (0) whx_w fp32->bf16 into d_ws (full 640x256; scan uses cols 0..127,
//      zx_gemm uses cols 128..255).
//  (1) zx_gemm: Zx[t*256+b][640] = W_x @ embed[ids[b,t]][0:128] + bias, fp32,
//      full-GPU MFMA GEMM (M=640,N=32768,K=128) with fused gather+bias.
//      This removes the scan-independent HALF of the recurrent MFMA work
//      from the 16-CU serial scan and runs it on 256 CUs.
//  (2) scan: 16 blocks x 512 threads, W_h register-resident (wf[5][4]),
//      acc init = prefetched Zx (register double-buffer, literal-indexed),
//      right_c read fp32 straight from embed via LDS-staged ids,
//      ONE barrier/step, h LDS XOR-swizzled (2-way-conflict-free).

constexpr int kL      = 128;
constexpr int kState  = 128;
constexpr int kInit   = 256;
constexpr int kRows   = 16;
constexpr int kBlocks = 16;
constexpr int kThreads= 512;
constexpr int kWElems = 5 * kState * kInit;     // 163840 (320 KiB bf16)
constexpr int kNTot   = 256 * kL;               // 32768 (t,b) rows
constexpr int kZxCols = 5 * kState;             // 640

typedef __attribute__((ext_vector_type(8))) short short8;    // MFMA A/B frag
typedef __attribute__((ext_vector_type(4))) short short4v;
typedef __attribute__((ext_vector_type(4))) float floatx4;   // MFMA C/D frag

__device__ __forceinline__ uint16_t f2bf(float f) {
    union { float f; uint32_t i; } v; v.f = f;
    return (uint16_t)((v.i + 0x7FFFu + ((v.i >> 16) & 1u)) >> 16);  // RNE
}
__device__ __forceinline__ float bf2f(uint16_t u) {
    union { uint32_t i; float f; } v; v.i = ((uint32_t)u) << 16; return v.f;
}
__device__ __forceinline__ float clampf(float x, float lo, float hi) {
    return fminf(fmaxf(x, lo), hi);
}

// ---- kernel 0: whx_w fp32 -> bf16 (row-major 640x256) ----
__global__ __launch_bounds__(256)
void convert_weights_kernel(const float* __restrict__ wsrc,
                            uint16_t* __restrict__ wdst) {
    int i = blockIdx.x * 256 + threadIdx.x;          // float4 index
    float4 v = ((const float4*)wsrc)[i];
    uint16_t q[4] = { f2bf(v.x), f2bf(v.y), f2bf(v.z), f2bf(v.w) };
    ((short4v*)wdst)[i] = *(short4v*)q;
}

// ---- kernel 1: Zx[n][j] = sum_k W[j][128+k]*embed[id(n)][k] + bias[j] ----
// n = t*256 + b. Per wave: one 16-n tile, full j=0..639.
// A-frag = X (lane&15 = n-local row, k = kk*32 + quad*8 + e), bf16-converted
// on the fly. B-frag = W x-part (lane&15 = j col). D: row=n-local(quad*4+r),
// col=j(l15) -> stores are 64B-coalesced over l15.
__global__ __launch_bounds__(256)
void zx_gemm_kernel(const uint16_t* __restrict__ wbf,
                    const float* __restrict__ embed,
                    const int* __restrict__ ids,
                    const float* __restrict__ whx_b,
                    float* __restrict__ zx)
{
    const int wv   = threadIdx.x >> 6;
    const int lane = threadIdx.x & 63;
    const int l15  = lane & 15;
    const int quad = lane >> 4;
    const int n0   = (blockIdx.x * 4 + wv) * 16;
    const int T    = n0 >> 8;                  // timestep
    const int B    = (n0 & 255) + l15;         // batch row for this lane
    const int id   = ids[B * kL + T];

    short8 af[4];
    const float* xr = embed + (size_t)id * kInit;   // right_h = cols 0..127
#pragma unroll
    for (int kk = 0; kk < 4; ++kk) {
        float4 v0 = *(const float4*)(xr + kk * 32 + quad * 8);
        float4 v1 = *(const float4*)(xr + kk * 32 + quad * 8 + 4);
        uint16_t q[8] = { f2bf(v0.x), f2bf(v0.y), f2bf(v0.z), f2bf(v0.w),
                          f2bf(v1.x), f2bf(v1.y), f2bf(v1.z), f2bf(v1.w) };
        af[kk] = *(short8*)q;
    }

    float* zrow = zx + (size_t)n0 * kZxCols;
#pragma unroll 4
    for (int jf = 0; jf < 40; ++jf) {
        const int j = jf * 16 + l15;
        const uint16_t* wr = wbf + (size_t)j * kInit + kState;  // x-part cols
        float bj = whx_b[j];
        floatx4 acc = { bj, bj, bj, bj };
#pragma unroll
        for (int kk = 0; kk < 4; ++kk) {
            short8 bfr = *(const short8*)(wr + kk * 32 + quad * 8);
            acc = __builtin_amdgcn_mfma_f32_16x16x32_bf16(af[kk], bfr, acc, 0, 0, 0);
        }
#pragma unroll
        for (int r = 0; r < 4; ++r)
            zrow[(size_t)(quad * 4 + r) * kZxCols + j] = acc[r];
    }
}

// ---- kernel 2: the scan (h-recurrence only, K=128) ----
__global__ __launch_bounds__(kThreads)
__attribute__((amdgpu_waves_per_eu(1, 2)))
void tree_lstm_kernel(const uint16_t* __restrict__ wbf,
                      const float* __restrict__ zx,
                      const float* __restrict__ embed,
                      const int* __restrict__ ids,
                      const float* __restrict__ init_state,
                      const float* __restrict__ final_w,
                      const float* __restrict__ final_b,
                      float* __restrict__ out)
{
    // swizzled: element (row, col) lives at [row][ ((col>>3)^row)*8 + (col&7) ]
    __shared__ alignas(16) uint16_t hb[2][kRows][kState];   // 8 KB  (h)
    __shared__ int ids_l[kL][kRows];                        // 8 KB, [t][b]
    __shared__ float partial[kRows][3][4];
    // >80 KiB total => exactly 1 workgroup/CU (proven to materialize in R6).
    __shared__ float lds_force_pad[16384];                  // 64 KiB

    const int tid  = threadIdx.x;
    const int w    = tid >> 6;        // wave 0..7 -> j-slice [16w,16w+16)
    const int lane = tid & 63;
    const int l15  = lane & 15;       // batch row (MFMA D col / B col)
    const int quad = lane >> 4;       // 0..3
    const int b0   = blockIdx.x * kRows;
    const int j0   = w * 16 + quad * 4;   // 4 consecutive j (MFMA D rows)

    if (__builtin_expect(ids[0] < 0, 0)) {      // never true; keeps pad alive
        volatile float* vp = lds_force_pad;
        vp[tid] = (float)tid;
        float v = vp[(tid * 7) & 16383];
        if (v < -1.0e30f) out[0] = v;
    }

    // stage ids transposed [t][b] (conflict-free per-step lookup)
    for (int i = tid; i < kL * kRows; i += kThreads)
        ids_l[i >> 4][i & 15] = ids[(b0 + (i & 15)) * kL + (i >> 4)];

    // register-resident A-frags, h-part only (cols 0..127): 80 VGPRs
    short8 wf[5][4];
#pragma unroll
    for (int g = 0; g < 5; ++g) {
        const uint16_t* wrow = wbf + (size_t)(g * 128 + w * 16 + l15) * kInit;
#pragma unroll
        for (int kk = 0; kk < 4; ++kk)
            wf[g][kk] = *(const short8*)(wrow + kk * 32 + quad * 8);
    }

    // h0 (bf16, swizzled into hb[0]) and c0 (fp32 regs), broadcast over batch
    const int ch2  = 2 * w + (quad >> 1);                // h chunk of j0
    const int hoff = (ch2 ^ l15) * 8 + (quad & 1) * 4;   // elem offset in row
    float c_reg[4];
    {
        uint16_t h0[4];
#pragma unroll
        for (int r = 0; r < 4; ++r) {
            h0[r]    = f2bf(init_state[j0 + r]);
            c_reg[r] = init_state[128 + j0 + r];
        }
        *(short4v*)&hb[0][l15][hoff] = *(short4v*)h0;
    }
    __syncthreads();   // ids_l + h0 visible

    // register double-buffer for Zx (acc init) and right_c; literal-indexed
    floatx4 zbuf[2][5];
    floatx4 rbuf[2];
    {
        const float* zr = zx + ((size_t)b0 + l15) * kZxCols + j0;   // t=0
#pragma unroll
        for (int g = 0; g < 5; ++g)
            zbuf[0][g] = *(const floatx4*)(zr + g * 128);
        int id0 = ids_l[0][l15];
        rbuf[0] = *(const floatx4*)(embed + (size_t)id0 * kInit + kState + j0);
    }

    const float K1 = 1.442695041f;   // log2(e)
    const float K2 = 2.885390082f;   // 2*log2(e)

#define LSTM_STEP(T, CUR, NXT)                                                 \
    {                                                                          \
        /* prefetch t+1 into the other register buffer (hidden by step) */     \
        int tn = (T) + 1; if (tn >= kL) tn = kL - 1;                           \
        const float* zr = zx + ((size_t)tn * 256 + b0 + l15) * kZxCols + j0;   \
        _Pragma("unroll")                                                      \
        for (int g = 0; g < 5; ++g)                                            \
            zbuf[NXT][g] = *(const floatx4*)(zr + g * 128);                    \
        int idn = ids_l[tn][l15];                                              \
        rbuf[NXT] = *(const floatx4*)(embed + (size_t)idn * kInit + kState + j0); \
        /* acc init = Zx (x-part + bias), then h-part MFMAs */                 \
        floatx4 acc[5];                                                        \
        _Pragma("unroll")                                                      \
        for (int g = 0; g < 5; ++g) acc[g] = zbuf[CUR][g];                     \
        const uint16_t* hrow = &hb[CUR][l15][0];                               \
        _Pragma("unroll")                                                      \
        for (int kk = 0; kk < 4; ++kk) {                                       \
            short8 xf = *(const short8*)(hrow + ((kk * 4 + quad) ^ l15) * 8);  \
            _Pragma("unroll")                                                  \
            for (int g = 0; g < 5; ++g)                                        \
                acc[g] = __builtin_amdgcn_mfma_f32_16x16x32_bf16(              \
                    wf[g][kk], xf, acc[g], 0, 0, 0);                           \
        }                                                                      \
        uint16_t hv[4];                                                        \
        _Pragma("unroll")                                                      \
        for (int r = 0; r < 4; ++r) {                                          \
            float a  = clampf(acc[0][r], -15.f, 15.f);                         \
            float ii = clampf(acc[1][r], -30.f, 30.f);                         \
            float f1 = clampf(acc[2][r], -30.f, 30.f);                         \
            float f2 = clampf(acc[3][r], -30.f, 30.f);                         \
            float oo = clampf(acc[4][r], -30.f, 30.f);                         \
            float Ea = exp2f(a * K2);                                          \
            float Ei = exp2f(-ii * K1);                                        \
            float P  = (Ea - 1.0f) *                                           \
                __builtin_amdgcn_rcpf((Ea + 1.0f) * (1.0f + Ei));              \
            float E1 = exp2f(f1 * K1), E2 = exp2f(f2 * K1);                    \
            float lc = c_reg[r], rc = rbuf[CUR][r];                            \
            float num = E1 * (1.0f + E2) * lc + E2 * (1.0f + E1) * rc;         \
            float Q  = num * __builtin_amdgcn_rcpf((1.0f + E1) * (1.0f + E2)); \
            float c  = P + Q;                                                  \
            c_reg[r] = c;                                                      \
            float Eo = exp2f(-oo * K1);                                        \
            float cc = clampf(c, -15.f, 15.f);                                 \
            float Ec = exp2f(cc * K2);                                         \
            float h  = (Ec - 1.0f) *                                           \
                __builtin_amdgcn_rcpf((1.0f + Eo) * (Ec + 1.0f));              \
            hv[r] = f2bf(h);                                                   \
        }                                                                      \
        *(short4v*)&hb[NXT][l15][hoff] = *(short4v*)hv;                        \
        __syncthreads();   /* single barrier: publishes h */                   \
    }

#pragma unroll 1
    for (int t2 = 0; t2 < kL; t2 += 2) {
        LSTM_STEP(t2, 0, 1)
        LSTM_STEP(t2 + 1, 1, 0)
    }
#undef LSTM_STEP

    // final: out[b][o] = sum_j h[b][j]*final_w[o][j] + final_b[o]
    // final h is in hb[0] (t=127 wrote NXT=0), swizzled
    if (tid < 192) {
        int b = tid / 12, rem = tid % 12;
        int o = rem >> 2, q4 = rem & 3;
        float s = 0.f;
        const float* wrow = final_w + o * kState;
#pragma unroll 8
        for (int j = q4 * 32; j < q4 * 32 + 32; ++j) {
            uint16_t hval = hb[0][b][((j >> 3) ^ b) * 8 + (j & 7)];
            s += bf2f(hval) * wrow[j];
        }
        partial[b][o][q4] = s;
    }
    __syncthreads();
    if (tid < 48) {
        int b = tid / 3, o = tid % 3;
        float s = partial[b][o][0] + partial[b][o][1] +
                  partial[b][o][2] + partial[b][o][3] + final_b[o];
        out[(b0 + b) * 3 + o] = s;
    }
}

extern "C" void kernel_launch(void* const* d_in, const int* in_sizes, int n_in,
                              void* d_out, int out_size, void* d_ws, size_t ws_size,
                              hipStream_t stream) {
    const int*   ids        = (const int*)d_in[0];
    const float* embed      = (const float*)d_in[1];
    const float* whx_w      = (const float*)d_in[2];
    const float* whx_b      = (const float*)d_in[3];
    const float* init_state = (const float*)d_in[4];
    const float* final_w    = (const float*)d_in[5];
    const float* final_b    = (const float*)d_in[6];
    float*       out        = (float*)d_out;
    uint16_t*    wbf        = (uint16_t*)d_ws;                         // 320 KiB
    float*       zx         = (float*)((char*)d_ws + (size_t)kWElems * 2); // 83.9 MB

    convert_weights_kernel<<<kWElems / 4 / 256, 256, 0, stream>>>(whx_w, wbf);
    zx_gemm_kernel<<<kNTot / 64, 256, 0, stream>>>(wbf, embed, ids, whx_b, zx);
    tree_lstm_kernel<<<kBlocks, kThreads, 0, stream>>>(
        wbf, zx, embed, ids, init_state, final_w, final_b, out);
}

// Round 2
// 311.016 us; speedup vs baseline: 1.0910x; 1.0910x over previous
//
#include <hip/hip_runtime.h>
#include <stdint.h>

// Tree-LSTM scan: B=256, L=128, STATE=128, INIT=256, Z=5*128=640. fp32 I/O.
// Pipeline:
//  (0) whx_w fp32->bf16 into d_ws (full 640x256).
//  (1) zx_gemm: Zx[t*256+b][640] = W_x @ embed[ids[b,t]][0:128] + bias, fp32,
//      full-GPU MFMA GEMM with fused gather+bias (runs on 256 CUs).
//  (2) scan: 32 blocks x 512 threads, 8 batch rows/block. The MFMA's 16
//      B-columns hold batch 0..7 MIRRORED (hb rows 8..15 duplicate 0..7, Zx
//      C-init row clamped to l15&7) so D cols 8..15 are exact copies of
//      0..7: lanes l15>=8 own gate r-slots {2,3} with NO shuffles, halving
//      gate VALU per lane and doubling active CUs. W_h register-resident,
//      ONE barrier/step, h LDS XOR-swizzled.

constexpr int kL      = 128;
constexpr int kState  = 128;
constexpr int kInit   = 256;
constexpr int kRows   = 8;                      // batch rows per scan block
constexpr int kBlocks = 32;
constexpr int kThreads= 512;
constexpr int kWElems = 5 * kState * kInit;     // 163840 (320 KiB bf16)
constexpr int kNTot   = 256 * kL;               // 32768 (t,b) rows
constexpr int kZxCols = 5 * kState;             // 640

typedef __attribute__((ext_vector_type(8))) short short8;    // MFMA A/B frag
typedef __attribute__((ext_vector_type(4))) short short4v;
typedef __attribute__((ext_vector_type(4))) float floatx4;   // MFMA C/D frag

__device__ __forceinline__ uint16_t f2bf(float f) {
    union { float f; uint32_t i; } v; v.f = f;
    return (uint16_t)((v.i + 0x7FFFu + ((v.i >> 16) & 1u)) >> 16);  // RNE
}
__device__ __forceinline__ float bf2f(uint16_t u) {
    union { uint32_t i; float f; } v; v.i = ((uint32_t)u) << 16; return v.f;
}

// ---- kernel 0: whx_w fp32 -> bf16 (row-major 640x256) ----
__global__ __launch_bounds__(256)
void convert_weights_kernel(const float* __restrict__ wsrc,
                            uint16_t* __restrict__ wdst) {
    int i = blockIdx.x * 256 + threadIdx.x;          // float4 index
    float4 v = ((const float4*)wsrc)[i];
    uint16_t q[4] = { f2bf(v.x), f2bf(v.y), f2bf(v.z), f2bf(v.w) };
    ((short4v*)wdst)[i] = *(short4v*)q;
}

// ---- kernel 1: Zx[n][j] = sum_k W[j][128+k]*embed[id(n)][k] + bias[j] ----
__global__ __launch_bounds__(256)
void zx_gemm_kernel(const uint16_t* __restrict__ wbf,
                    const float* __restrict__ embed,
                    const int* __restrict__ ids,
                    const float* __restrict__ whx_b,
                    float* __restrict__ zx)
{
    const int wv   = threadIdx.x >> 6;
    const int lane = threadIdx.x & 63;
    const int l15  = lane & 15;
    const int quad = lane >> 4;
    const int n0   = (blockIdx.x * 4 + wv) * 16;
    const int T    = n0 >> 8;                  // timestep
    const int B    = (n0 & 255) + l15;         // batch row for this lane
    const int id   = ids[B * kL + T];

    short8 af[4];
    const float* xr = embed + (size_t)id * kInit;   // right_h = cols 0..127
#pragma unroll
    for (int kk = 0; kk < 4; ++kk) {
        float4 v0 = *(const float4*)(xr + kk * 32 + quad * 8);
        float4 v1 = *(const float4*)(xr + kk * 32 + quad * 8 + 4);
        uint16_t q[8] = { f2bf(v0.x), f2bf(v0.y), f2bf(v0.z), f2bf(v0.w),
                          f2bf(v1.x), f2bf(v1.y), f2bf(v1.z), f2bf(v1.w) };
        af[kk] = *(short8*)q;
    }

    float* zrow = zx + (size_t)n0 * kZxCols;
#pragma unroll 4
    for (int jf = 0; jf < 40; ++jf) {
        const int j = jf * 16 + l15;
        const uint16_t* wr = wbf + (size_t)j * kInit + kState;  // x-part cols
        float bj = whx_b[j];
        floatx4 acc = { bj, bj, bj, bj };
#pragma unroll
        for (int kk = 0; kk < 4; ++kk) {
            short8 bfr = *(const short8*)(wr + kk * 32 + quad * 8);
            acc = __builtin_amdgcn_mfma_f32_16x16x32_bf16(af[kk], bfr, acc, 0, 0, 0);
        }
#pragma unroll
        for (int r = 0; r < 4; ++r)
            zrow[(size_t)(quad * 4 + r) * kZxCols + j] = acc[r];
    }
}

// ---- kernel 2: the scan (h-recurrence only, K=128) ----
__global__ __launch_bounds__(kThreads)
__attribute__((amdgpu_waves_per_eu(1, 2)))
void tree_lstm_kernel(const uint16_t* __restrict__ wbf,
                      const float* __restrict__ zx,
                      const float* __restrict__ embed,
                      const int* __restrict__ ids,
                      const float* __restrict__ init_state,
                      const float* __restrict__ final_w,
                      const float* __restrict__ final_b,
                      float* __restrict__ out)
{
    // swizzled: element (row, col) lives at [row][ ((col>>3)^row)*8 + (col&7) ]
    // rows 8..15 mirror rows 0..7 (dual-write) -> MFMA D cols 8..15 mirror.
    __shared__ alignas(16) uint16_t hb[2][16][kState];      // 8 KB  (h)
    __shared__ int ids_l[kL][kRows];                        // 4 KB, [t][b]
    __shared__ float partial[kRows][3][4];
    // >80 KiB total => exactly 1 workgroup/CU.
    __shared__ float lds_force_pad[18432];                  // 72 KiB

    const int tid  = threadIdx.x;
    const int w    = tid >> 6;        // wave 0..7 -> j-slice [16w,16w+16)
    const int lane = tid & 63;
    const int l15  = lane & 15;       // MFMA D col (batch, mirrored over 8)
    const int quad = lane >> 4;       // 0..3
    const int b0   = blockIdx.x * kRows;
    const int j0   = w * 16 + quad * 4;   // 4 consecutive j (MFMA D rows)
    const int bl   = l15 & 7;             // owned batch row
    const bool hig = l15 >= 8;            // owns r-slots {2,3}
    const int jp   = j0 + (hig ? 2 : 0);  // first owned j

    if (__builtin_expect(ids[0] < 0, 0)) {      // never true; keeps pad alive
        volatile float* vp = lds_force_pad;
        vp[tid] = (float)tid;
        float v = vp[(tid * 7) & 16383];
        if (v < -1.0e30f) out[0] = v;
    }

    // stage ids transposed [t][b]
    for (int i = tid; i < kL * kRows; i += kThreads)
        ids_l[i >> 3][i & 7] = ids[(b0 + (i & 7)) * kL + (i >> 3)];

    // register-resident A-frags, h-part only (cols 0..127): 40 VGPRs
    short8 wf[5][4];
#pragma unroll
    for (int g = 0; g < 5; ++g) {
        const uint16_t* wrow = wbf + (size_t)(g * 128 + w * 16 + l15) * kInit;
#pragma unroll
        for (int kk = 0; kk < 4; ++kk)
            wf[g][kk] = *(const short8*)(wrow + kk * 32 + quad * 8);
    }

    // h0 (bf16, swizzled into hb[0]; all 16 rows incl. mirrors get identical
    // broadcast values) and c0 (fp32 regs for the 2 owned slots)
    const int g8   = 2 * w + (quad >> 1);                // col group of j0/jp
    const int hoff = (g8 ^ l15) * 8 + (quad & 1) * 4;    // h0 write offset
    float c_reg[2];
    {
        uint16_t h0[4];
#pragma unroll
        for (int r = 0; r < 4; ++r)
            h0[r] = f2bf(init_state[j0 + r]);
        c_reg[0] = init_state[128 + jp];
        c_reg[1] = init_state[128 + jp + 1];
        *(short4v*)&hb[0][l15][hoff] = *(short4v*)h0;
    }
    __syncthreads();   // ids_l + h0 visible

    // per-step h write: 2 bf16 (4 B) to row bl AND mirror row bl+8
    const int eoff  = (quad & 1) * 4 + (hig ? 2 : 0);    // jp & 7
    const int wlo   = (g8 ^ bl) * 8 + eoff;
    const int whi   = ((g8 ^ bl) ^ 8) * 8 + eoff;

    // register double-buffer for Zx (acc init; row clamped to bl so mirror
    // cols get duplicates) and right_c (2 owned values); literal-indexed
    floatx4 zbuf[2][5];
    float2  rbuf[2];
    {
        const float* zr = zx + ((size_t)b0 + bl) * kZxCols + j0;   // t=0
#pragma unroll
        for (int g = 0; g < 5; ++g)
            zbuf[0][g] = *(const floatx4*)(zr + g * 128);
        int id0 = ids_l[0][bl];
        rbuf[0] = *(const float2*)(embed + (size_t)id0 * kInit + kState + jp);
    }

    const float K1 = 1.442695041f;   // log2(e)
    const float K2 = 2.885390082f;   // 2*log2(e)

    // One gate cell. RL = literal r (0/1); select mirrors via cndmask.
    // fminf-only clamps: unclamped directions are safe (Inf -> rcp -> 0).
#define GATE_CELL(RL, RCV, HVOUT)                                              \
    {                                                                          \
        float ga = hig ? acc[0][RL + 2] : acc[0][RL];                          \
        float gi = hig ? acc[1][RL + 2] : acc[1][RL];                          \
        float g1 = hig ? acc[2][RL + 2] : acc[2][RL];                          \
        float g2 = hig ? acc[3][RL + 2] : acc[3][RL];                          \
        float go = hig ? acc[4][RL + 2] : acc[4][RL];                          \
        float a  = fminf(ga, 15.f);                                            \
        float f1 = fminf(g1, 30.f);                                            \
        float f2 = fminf(g2, 30.f);                                            \
        float Ea = exp2f(a * K2);                 /* e^{2a} */                 \
        float Ei = exp2f(-gi * K1);               /* e^{-i} */                 \
        float P  = (Ea - 1.0f) *                                               \
            __builtin_amdgcn_rcpf((Ea + 1.0f) * (1.0f + Ei));                  \
        float E1 = exp2f(f1 * K1), E2 = exp2f(f2 * K1);                        \
        float lc = c_reg[RL], rc = (RCV);                                      \
        float num = E1 * (1.0f + E2) * lc + E2 * (1.0f + E1) * rc;             \
        float Q  = num * __builtin_amdgcn_rcpf((1.0f + E1) * (1.0f + E2));     \
        float c  = P + Q;                                                      \
        c_reg[RL] = c;                                                         \
        float Eo = exp2f(-go * K1);                                            \
        float cc = fminf(c, 15.f);                                             \
        float Ec = exp2f(cc * K2);                                             \
        float h  = (Ec - 1.0f) *                                               \
            __builtin_amdgcn_rcpf((1.0f + Eo) * (Ec + 1.0f));                  \
        HVOUT = f2bf(h);                                                       \
    }

#define LSTM_STEP(T, CUR, NXT)                                                 \
    {                                                                          \
        /* prefetch t+1 into the other register buffer (hidden by step) */     \
        int tn = (T) + 1; if (tn >= kL) tn = kL - 1;                           \
        const float* zr = zx + ((size_t)tn * 256 + b0 + bl) * kZxCols + j0;    \
        _Pragma("unroll")                                                      \
        for (int g = 0; g < 5; ++g)                                            \
            zbuf[NXT][g] = *(const floatx4*)(zr + g * 128);                    \
        int idn = ids_l[tn][bl];                                               \
        rbuf[NXT] = *(const float2*)(embed + (size_t)idn * kInit + kState + jp); \
        /* acc init = Zx (x-part + bias), then h-part MFMAs */                 \
        floatx4 acc[5];                                                        \
        _Pragma("unroll")                                                      \
        for (int g = 0; g < 5; ++g) acc[g] = zbuf[CUR][g];                     \
        const uint16_t* hrow = &hb[CUR][l15][0];                               \
        _Pragma("unroll")                                                      \
        for (int kk = 0; kk < 4; ++kk) {                                       \
            short8 xf = *(const short8*)(hrow + ((kk * 4 + quad) ^ l15) * 8);  \
            _Pragma("unroll")                                                  \
            for (int g = 0; g < 5; ++g)                                        \
                acc[g] = __builtin_amdgcn_mfma_f32_16x16x32_bf16(              \
                    wf[g][kk], xf, acc[g], 0, 0, 0);                           \
        }                                                                      \
        uint16_t hv0, hv1;                                                     \
        GATE_CELL(0, rbuf[CUR].x, hv0)                                         \
        GATE_CELL(1, rbuf[CUR].y, hv1)                                         \
        uint32_t hp = (uint32_t)hv0 | ((uint32_t)hv1 << 16);                   \
        *(uint32_t*)&hb[NXT][bl][wlo]     = hp;                                \
        *(uint32_t*)&hb[NXT][bl + 8][whi] = hp;                                \
        __syncthreads();   /* single barrier: publishes h */                   \
    }

#pragma unroll 1
    for (int t2 = 0; t2 < kL; t2 += 2) {
        LSTM_STEP(t2, 0, 1)
        LSTM_STEP(t2 + 1, 1, 0)
    }
#undef LSTM_STEP
#undef GATE_CELL

    // final: out[b][o] = sum_j h[b][j]*final_w[o][j] + final_b[o]
    // final h is in hb[0] (t=127 wrote NXT=0), swizzled; rows 0..7 valid
    if (tid < kRows * 12) {
        int b = tid / 12, rem = tid % 12;
        int o = rem >> 2, q4 = rem & 3;
        float s = 0.f;
        const float* wrow = final_w + o * kState;
#pragma unroll 8
        for (int j = q4 * 32; j < q4 * 32 + 32; ++j) {
            uint16_t hval = hb[0][b][((j >> 3) ^ b) * 8 + (j & 7)];
            s += bf2f(hval) * wrow[j];
        }
        partial[b][o][q4] = s;
    }
    __syncthreads();
    if (tid < kRows * 3) {
        int b = tid / 3, o = tid % 3;
        float s = partial[b][o][0] + partial[b][o][1] +
                  partial[b][o][2] + partial[b][o][3] + final_b[o];
        out[(b0 + b) * 3 + o] = s;
    }
}

extern "C" void kernel_launch(void* const* d_in, const int* in_sizes, int n_in,
                              void* d_out, int out_size, void* d_ws, size_t ws_size,
                              hipStream_t stream) {
    const int*   ids        = (const int*)d_in[0];
    const float* embed      = (const float*)d_in[1];
    const float* whx_w      = (const float*)d_in[2];
    const float* whx_b      = (const float*)d_in[3];
    const float* init_state = (const float*)d_in[4];
    const float* final_w    = (const float*)d_in[5];
    const float* final_b    = (const float*)d_in[6];
    float*       out        = (float*)d_out;
    uint16_t*    wbf        = (uint16_t*)d_ws;                         // 320 KiB
    float*       zx         = (float*)((char*)d_ws + (size_t)kWElems * 2); // 83.9 MB

    convert_weights_kernel<<<kWElems / 4 / 256, 256, 0, stream>>>(whx_w, wbf);
    zx_gemm_kernel<<<kNTot / 64, 256, 0, stream>>>(wbf, embed, ids, whx_b, zx);
    tree_lstm_kernel<<<kBlocks, kThreads, 0, stream>>>(
        wbf, zx, embed, ids, init_state, final_w, final_b, out);
}